// Round 1
// baseline (1334.980 us; speedup 1.0000x reference)
//
#include <hip/hip_runtime.h>
#include <stdint.h>

typedef short bf16x8 __attribute__((ext_vector_type(8)));
typedef float f32x4 __attribute__((ext_vector_type(4)));

#define N_IMG 128
#define C_IN 512
#define NP1 25
#define C1 537
#define C1P 576               // padded to 9*64 for BK=64
#define HID 256
#define RR 28
#define PLANE 784               // 28*28
#define P_TOTAL (N_IMG * PLANE) // 100352

// halo tile geometry: block owns 4 output rows x 28 cols of one image,
// all 256 output channels. Input halo rows h0-2..h0+6 (dh in {-2..3}),
// cols -3..29 (dw in {-3..2}).
#define TILE_H 4
#define HALO_H 9
#define HALO_W 33
#define RC_SLOTS (HALO_H * HALO_W)   // 297 (row,col) cells
#define GRAN_REAL (RC_SLOTS * 8)     // 2376 16B granules per 64-ch chunk
#define GRAN_PAD 2560                // 10 staging iters * 256 threads
#define BUF_U16 (GRAN_PAD * 8)       // 20480 uint16 per buffer (40960 B)

// zero-initialized device BSS, never written -> stays zero across calls.
// OOB halo reads redirect here. Max offset read: 8*128 + 16 = 1040 B < 4 KB.
__device__ __align__(16) uint16_t g_zeropage[2048];

__device__ __forceinline__ uint16_t f2bf(float f) {
  union { float f; uint32_t u; } v; v.f = f;
  return (uint16_t)((v.u + 0x7fffu + ((v.u >> 16) & 1u)) >> 16);
}

__device__ __forceinline__ void load16(void* lds, const void* g) {
  __builtin_amdgcn_global_load_lds(
      (__attribute__((address_space(1))) void*)(g),
      (__attribute__((address_space(3))) void*)(lds), 16, 0, 0);
}

// ---------------- max-pool 4x4: fine_segm [128,25,112,112] -> pooled NCHW [128,25,28,28]
__global__ void pool_kernel(const float* __restrict__ fs, float* __restrict__ pooled) {
  int u = blockIdx.x * 256 + threadIdx.x;
  if (u >= N_IMG * NP1 * PLANE) return;
  int w = u % RR;
  int tmp = u / RR;
  int h = tmp % RR; tmp /= RR;
  int c = tmp % NP1;
  int n = tmp / NP1;
  const float* base = fs + (((size_t)(n * NP1 + c)) * 112 + h * 4) * 112 + w * 4;
  float m = -INFINITY;
#pragma unroll
  for (int i = 0; i < 4; i++) {
    float4 v = *(const float4*)(base + (size_t)i * 112);
    m = fmaxf(m, fmaxf(fmaxf(v.x, v.y), fmaxf(v.z, v.w)));
  }
  pooled[u] = m;
}

// ---------------- build X0: NCHW fp32 (features | pooled | zero-pad) -> NHWC bf16 [100352][576]
__global__ void build_x0(const float* __restrict__ feat, const float* __restrict__ pooled,
                         uint16_t* __restrict__ X0) {
  __shared__ float tile[64][65];
  const int n = blockIdx.z;
  const int c0 = blockIdx.y * 64;
  const int p0 = blockIdx.x * 64;
  const int tx = threadIdx.x & 63;  // pos
  const int ty = threadIdx.x >> 6;  // 0..3
  const int p = p0 + tx;
#pragma unroll
  for (int k = 0; k < 16; k++) {
    const int cl = ty + k * 4;
    const int c = c0 + cl;
    float v = 0.f;
    if (p < PLANE) {
      if (c < C_IN)
        v = feat[((size_t)(n * C_IN + c)) * PLANE + p];
      else if (c < C1)
        v = pooled[((size_t)(n * NP1 + (c - C_IN))) * PLANE + p];
    }
    tile[cl][tx] = v;
  }
  __syncthreads();
#pragma unroll
  for (int k = 0; k < 2; k++) {
    const int u = threadIdx.x + k * 256; // 0..511
    const int pl = u >> 3;               // 0..63
    const int ch = u & 7;                // 16B chunk (8 channels)
    if (p0 + pl < PLANE) {
      bf16x8 v;
#pragma unroll
      for (int e = 0; e < 8; e++) v[e] = (short)f2bf(tile[ch * 8 + e][pl]);
      *(bf16x8*)&X0[((size_t)n * PLANE + p0 + pl) * C1P + c0 + ch * 8] = v;
    }
  }
}

// ---------------- weights fp32 [O,C,3,3] -> bf16 [9][256][CPAD] (c-contiguous, zero-padded)
__global__ void wconv_kernel(const float* __restrict__ w, uint16_t* __restrict__ wbf,
                             int C, int CPAD) {
  int v = blockIdx.x * 256 + threadIdx.x;
  if (v >= 9 * HID * CPAD) return;
  int c = v % CPAD;
  int tmp = v / CPAD;
  int o = tmp % HID;
  int t = tmp / HID;
  uint16_t out = 0;
  if (c < C) out = f2bf(w[((size_t)(o * C + c)) * 9 + t]);
  wbf[v] = out;
}

// ---------------- halo-reuse implicit-GEMM conv layer.
// Per block: 112 positions (4 rows x 28 cols, one image) x 256 out-channels.
// K-loop: 64-ch chunks outermost; per chunk the 9x33 halo patch is staged in
// LDS ONCE (double-buffered, global_load_lds, counted vmcnt) and all 9 taps
// read shifted windows from it. B goes global->reg (XCD-L2-resident weights).
// LDS granule layout: linear index ((r*33+c)*8 + (g ^ (c&7))) -> granule g of
// cell (r,c); XOR swizzle spreads the 128B cells across banks on ds_read_b128.
template <int CPAD, bool FINAL>
__global__ __launch_bounds__(256, 2) void conv_halo(const uint16_t* __restrict__ Xin,
                                                    const uint16_t* __restrict__ Wt,
                                                    uint16_t* __restrict__ Yout,
                                                    float* __restrict__ Fout) {
  constexpr int NK = CPAD / 64;
  constexpr int TDH[9] = {-1, -1, -1, 0, 0, -2, 0, 2, 3};
  constexpr int TDW[9] = {-3, -1, 1, 0, 2, 1, -1, 0, 1};

  __shared__ __align__(16) uint16_t Abuf[2][BUF_U16];

  const int tid = threadIdx.x;
  const int lane = tid & 63;
  const int wv = tid >> 6;      // wave 0..3 -> out-channel quarter
  const int l15 = lane & 15;
  const int q = lane >> 4;      // 0..3
  const int ocw = wv * 64;

  // XCD-chunked swizzle (896 = 8*112): each XCD gets 16 whole images ->
  // adjacent bands share halo rows in that XCD's L2.
  const int bid = blockIdx.x;
  const int logical = (bid & 7) * 112 + (bid >> 3);
  const int n = logical / 7;
  const int band = logical - n * 7;
  const int h0 = band * TILE_H;

  // staging source pointers: 10 slots/thread; slot s = it*256 + tid holds
  // granule g = (s&7) ^ (c&7) of halo cell (r,c). OOB -> zeropage.
  const char* srcp[10];
#pragma unroll
  for (int it = 0; it < 10; ++it) {
    const int s = it * 256 + tid;
    const int rc = s >> 3;
    const int r = rc / HALO_W;
    const int c = rc - r * HALO_W;
    const int g = (s & 7) ^ (c & 7);
    const int ih = h0 - 2 + r;
    const int ic = c - 3;
    const bool valid = (rc < RC_SLOTS) & (ih >= 0) & (ih < RR) & (ic >= 0) & (ic < RR);
    srcp[it] = valid
        ? (const char*)(Xin + ((size_t)(n * PLANE + ih * RR + ic)) * CPAD + g * 8)
        : (const char*)g_zeropage;
  }

  // per-M-fragment LDS read bases (7 fragments of 16 positions)
  int baseoff[7], key0[7];
#pragma unroll
  for (int m = 0; m < 7; ++m) {
    const int pos = m * 16 + l15;
    const int hr = pos / RR;
    const int wc = pos - hr * RR;
    baseoff[m] = ((hr + 2) * HALO_W + (wc + 3)) * 128;
    key0[m] = (wc + 3) & 7;
  }

  f32x4 acc[7][4];
#pragma unroll
  for (int m = 0; m < 7; ++m)
#pragma unroll
    for (int j = 0; j < 4; ++j) acc[m][j] = (f32x4){0.f, 0.f, 0.f, 0.f};

  // prologue: stage chunk 0 into buf0
#pragma unroll
  for (int it = 0; it < 10; ++it)
    load16((char*)Abuf[0] + it * 4096 + wv * 1024, srcp[it]);

#pragma unroll 1
  for (int kc = 0; kc < NK; ++kc) {
    const uint16_t* curbuf = Abuf[kc & 1];
    if (kc + 1 < NK) {
      char* nb = (char*)Abuf[(kc + 1) & 1];
      const int off = (kc + 1) * 128;
#pragma unroll
      for (int it = 0; it < 10; ++it)
        load16(nb + it * 4096 + wv * 1024, srcp[it] + off);
      // keep the 10 just-issued next-chunk loads in flight; drain older ones
      asm volatile("s_waitcnt vmcnt(10)" ::: "memory");
    } else {
      asm volatile("s_waitcnt vmcnt(0)" ::: "memory");
    }
    __builtin_amdgcn_s_barrier();
    asm volatile("" ::: "memory");

    const uint16_t* Wk = Wt + (size_t)kc * 64;
#pragma unroll
    for (int t = 0; t < 9; ++t) {
      const int dh = TDH[t], dw = TDW[t];
      const uint16_t* Wtap = Wk + (size_t)t * HID * CPAD;
      bf16x8 bfrag[2][4];
#pragma unroll
      for (int kh = 0; kh < 2; ++kh)
#pragma unroll
        for (int j = 0; j < 4; ++j)
          bfrag[kh][j] = *(const bf16x8*)(Wtap + (size_t)(ocw + j * 16 + l15) * CPAD +
                                          kh * 32 + q * 8);
      const int toff = (dh * HALO_W + dw) * 128;
#pragma unroll
      for (int kh = 0; kh < 2; ++kh) {
        const int kq = kh * 4 + q;
        bf16x8 af[7];
#pragma unroll
        for (int m = 0; m < 7; ++m) {
          const int boff = baseoff[m] + toff + ((kq ^ ((key0[m] + dw) & 7)) << 4);
          af[m] = *(const bf16x8*)((const char*)curbuf + boff);
        }
#pragma unroll
        for (int m = 0; m < 7; ++m)
#pragma unroll
          for (int j = 0; j < 4; ++j)
            acc[m][j] = __builtin_amdgcn_mfma_f32_16x16x32_bf16(af[m], bfrag[kh][j],
                                                                acc[m][j], 0, 0, 0);
      }
    }
    asm volatile("" ::: "memory");
    __builtin_amdgcn_s_barrier();
  }

  // epilogue: C/D mapping col=lane&15 (oc), row=(lane>>4)*4+reg (position)
  const int pbase = n * PLANE + h0 * RR;
  if (!FINAL) {
#pragma unroll
    for (int m = 0; m < 7; ++m) {
#pragma unroll
      for (int r = 0; r < 4; ++r) {
        const int gpos = pbase + m * 16 + q * 4 + r;
        uint16_t* row = Yout + (size_t)gpos * HID + ocw + l15;
#pragma unroll
        for (int j = 0; j < 4; ++j) row[j * 16] = f2bf(fmaxf(acc[m][j][r], 0.f));
      }
    }
  } else {
#pragma unroll
    for (int m = 0; m < 7; ++m) {
      const int p4 = m * 16 + q * 4;      // tile-local, multiple of 4, no row-cross
      const int hh = p4 / RR;
      const int ww = p4 - hh * RR;
#pragma unroll
      for (int j = 0; j < 4; ++j) {
        const int o = ocw + j * 16 + l15;
        f32x4 v = acc[m][j];
        v[0] = fmaxf(v[0], 0.f);
        v[1] = fmaxf(v[1], 0.f);
        v[2] = fmaxf(v[2], 0.f);
        v[3] = fmaxf(v[3], 0.f);
        *(f32x4*)(Fout + ((size_t)(n * HID + o)) * PLANE + (h0 + hh) * RR + ww) = v;
      }
    }
  }
}

extern "C" void kernel_launch(void* const* d_in, const int* in_sizes, int n_in,
                              void* d_out, int out_size, void* d_ws, size_t ws_size,
                              hipStream_t stream) {
  const float* feat = (const float*)d_in[0];
  const float* fseg = (const float*)d_in[1];
  const float* w1 = (const float*)d_in[2];
  const float* w2 = (const float*)d_in[3];
  const float* w3 = (const float*)d_in[4];
  const float* w4 = (const float*)d_in[5];
  float* out = (float*)d_out;

  uint8_t* p = (uint8_t*)d_ws;
  uint16_t* X0 = (uint16_t*)p; p += (size_t)P_TOTAL * C1P * 2;   // 115.6 MB
  uint16_t* XA = (uint16_t*)p; p += (size_t)P_TOTAL * HID * 2;   // 51.4 MB
  uint16_t* XB = (uint16_t*)p; p += (size_t)P_TOTAL * HID * 2;   // 51.4 MB
  float* pooled = (float*)p;   p += (size_t)N_IMG * NP1 * PLANE * 4; // 10.0 MB
  uint16_t* W1b = (uint16_t*)p; p += (size_t)9 * HID * C1P * 2;  // 2.65 MB
  uint16_t* W2b = (uint16_t*)p; p += (size_t)9 * HID * HID * 2;  // 1.18 MB
  uint16_t* W3b = (uint16_t*)p; p += (size_t)9 * HID * HID * 2;
  uint16_t* W4b = (uint16_t*)p; p += (size_t)9 * HID * HID * 2;

  // front-end
  pool_kernel<<<(N_IMG * NP1 * PLANE + 255) / 256, 256, 0, stream>>>(fseg, pooled);
  wconv_kernel<<<(9 * HID * C1P + 255) / 256, 256, 0, stream>>>(w1, W1b, C1, C1P);
  wconv_kernel<<<(9 * HID * HID + 255) / 256, 256, 0, stream>>>(w2, W2b, HID, HID);
  wconv_kernel<<<(9 * HID * HID + 255) / 256, 256, 0, stream>>>(w3, W3b, HID, HID);
  wconv_kernel<<<(9 * HID * HID + 255) / 256, 256, 0, stream>>>(w4, W4b, HID, HID);
  build_x0<<<dim3(13, 9, N_IMG), 256, 0, stream>>>(feat, pooled, X0);

  // 4 deform-conv layers: 896 blocks = 128 images x 7 bands
  const int cgrid = P_TOTAL / (TILE_H * RR);
  conv_halo<C1P, false><<<cgrid, 256, 0, stream>>>(X0, W1b, XA, nullptr);
  conv_halo<HID, false><<<cgrid, 256, 0, stream>>>(XA, W2b, XB, nullptr);
  conv_halo<HID, false><<<cgrid, 256, 0, stream>>>(XB, W3b, XA, nullptr);
  conv_halo<HID, true><<<cgrid, 256, 0, stream>>>(XA, W4b, nullptr, out);
}

// Round 2
// 998.497 us; speedup vs baseline: 1.3370x; 1.3370x over previous
//
#include <hip/hip_runtime.h>
#include <stdint.h>

typedef short bf16x8 __attribute__((ext_vector_type(8)));
typedef float f32x4 __attribute__((ext_vector_type(4)));

#define N_IMG 128
#define C_IN 512
#define NP1 25
#define C1 537
#define C1P 576               // padded to 9*64 for BK=64
#define HID 256
#define RR 28
#define PLANE 784               // 28*28
#define P_TOTAL (N_IMG * PLANE) // 100352

// halo tile geometry: block owns 4 output rows x 28 cols of one image,
// all 256 output channels. Input halo rows h0-2..h0+6 (dh in {-2..3}),
// cols -3..29 (dw in {-3..2}).
#define TILE_H 4
#define HALO_H 9
#define HALO_W 33
#define RC_SLOTS (HALO_H * HALO_W)   // 297 (row,col) cells
#define GRAN_PAD 2560                // 10 staging iters * 256 threads
#define BUF_U16 (GRAN_PAD * 8)       // 20480 uint16 per buffer (40960 B)

// zero-initialized device BSS, never written -> stays zero across calls.
// OOB halo reads redirect here. Max offset read: 8*128 + 16 B < 4 KB.
__device__ __align__(16) uint16_t g_zeropage[2048];

__device__ __forceinline__ uint16_t f2bf(float f) {
  union { float f; uint32_t u; } v; v.f = f;
  return (uint16_t)((v.u + 0x7fffu + ((v.u >> 16) & 1u)) >> 16);
}

__device__ __forceinline__ void load16(void* lds, const void* g) {
  __builtin_amdgcn_global_load_lds(
      (__attribute__((address_space(1))) void*)(g),
      (__attribute__((address_space(3))) void*)(lds), 16, 0, 0);
}

// ---------------- max-pool 4x4: fine_segm [128,25,112,112] -> pooled NCHW [128,25,28,28]
__global__ void pool_kernel(const float* __restrict__ fs, float* __restrict__ pooled) {
  int u = blockIdx.x * 256 + threadIdx.x;
  if (u >= N_IMG * NP1 * PLANE) return;
  int w = u % RR;
  int tmp = u / RR;
  int h = tmp % RR; tmp /= RR;
  int c = tmp % NP1;
  int n = tmp / NP1;
  const float* base = fs + (((size_t)(n * NP1 + c)) * 112 + h * 4) * 112 + w * 4;
  float m = -INFINITY;
#pragma unroll
  for (int i = 0; i < 4; i++) {
    float4 v = *(const float4*)(base + (size_t)i * 112);
    m = fmaxf(m, fmaxf(fmaxf(v.x, v.y), fmaxf(v.z, v.w)));
  }
  pooled[u] = m;
}

// ---------------- build X0: NCHW fp32 (features | pooled | zero-pad) -> NHWC bf16 [100352][576]
__global__ void build_x0(const float* __restrict__ feat, const float* __restrict__ pooled,
                         uint16_t* __restrict__ X0) {
  __shared__ float tile[64][65];
  const int n = blockIdx.z;
  const int c0 = blockIdx.y * 64;
  const int p0 = blockIdx.x * 64;
  const int tx = threadIdx.x & 63;  // pos
  const int ty = threadIdx.x >> 6;  // 0..3
  const int p = p0 + tx;
#pragma unroll
  for (int k = 0; k < 16; k++) {
    const int cl = ty + k * 4;
    const int c = c0 + cl;
    float v = 0.f;
    if (p < PLANE) {
      if (c < C_IN)
        v = feat[((size_t)(n * C_IN + c)) * PLANE + p];
      else if (c < C1)
        v = pooled[((size_t)(n * NP1 + (c - C_IN))) * PLANE + p];
    }
    tile[cl][tx] = v;
  }
  __syncthreads();
#pragma unroll
  for (int k = 0; k < 2; k++) {
    const int u = threadIdx.x + k * 256; // 0..511
    const int pl = u >> 3;               // 0..63
    const int ch = u & 7;                // 16B chunk (8 channels)
    if (p0 + pl < PLANE) {
      bf16x8 v;
#pragma unroll
      for (int e = 0; e < 8; e++) v[e] = (short)f2bf(tile[ch * 8 + e][pl]);
      *(bf16x8*)&X0[((size_t)n * PLANE + p0 + pl) * C1P + c0 + ch * 8] = v;
    }
  }
}

// ---------------- weights fp32 [O,C,3,3] -> bf16 fragment-ordered layout:
// frag index = ((((t*NK + kc)*4 + wv)*2 + kh)*4 + j)*64 + lane, 8 ch each.
// o = wv*64 + j*16 + (lane&15); ch = kc*64 + kh*32 + (lane>>4)*8 + e.
// Makes every MFMA B-fragment load a lane-consecutive, fully-coalesced 1KB read.
__global__ void wconv_kernel(const float* __restrict__ w, uint16_t* __restrict__ wbf,
                             int C, int CPAD) {
  const int NK = CPAD / 64;
  int v = blockIdx.x * 256 + threadIdx.x;
  if (v >= 9 * HID * CPAD) return;
  const int e = v & 7;
  const int lane = (v >> 3) & 63;
  const int j = (v >> 9) & 3;
  const int kh = (v >> 11) & 1;
  const int wv = (v >> 12) & 3;
  const int u = v >> 14;
  const int kc = u % NK;
  const int t = u / NK;
  const int o = wv * 64 + j * 16 + (lane & 15);
  const int ch = kc * 64 + kh * 32 + (lane >> 4) * 8 + e;
  uint16_t out = 0;
  if (ch < C) out = f2bf(w[((size_t)(o * C + ch)) * 9 + t]);
  wbf[v] = out;
}

// ---------------- halo-reuse implicit-GEMM conv layer.
// Per block: 112 positions (4 rows x 28 cols, one image) x 256 out-channels.
// K-loop: 64-ch chunks outermost; per chunk the 9x33 halo patch is staged in
// LDS ONCE (double-buffered, global_load_lds, counted vmcnt) and all 9 taps
// read shifted windows from it. B fragments come from the fragment-ordered
// weight array (coalesced, XCD-L2-resident).
// LDS granule layout: linear slot s -> cell rc=s>>3, slot s&7 holds global
// granule g = (s&7) ^ ((c + 4*r)&7). The +4r term makes the key congruent to
// (c0 + lane) mod 8 even across 28-col row wraps (28 == 4 mod 8), so every
// 16-lane fragment read is a uniform free 2-way bank access.
template <int CPAD, bool FINAL>
__global__ __launch_bounds__(256, 2) void conv_halo(const uint16_t* __restrict__ Xin,
                                                    const uint16_t* __restrict__ Wt,
                                                    uint16_t* __restrict__ Yout,
                                                    float* __restrict__ Fout) {
  constexpr int NK = CPAD / 64;
  constexpr int TDH[9] = {-1, -1, -1, 0, 0, -2, 0, 2, 3};
  constexpr int TDW[9] = {-3, -1, 1, 0, 2, 1, -1, 0, 1};

  __shared__ __align__(16) uint16_t Abuf[2][BUF_U16];

  const int tid = threadIdx.x;
  const int lane = tid & 63;
  const int wv = tid >> 6;      // wave 0..3 -> out-channel quarter
  const int l15 = lane & 15;
  const int q = lane >> 4;      // 0..3
  const int ocw = wv * 64;

  // XCD-chunked swizzle (896 = 8*112): each XCD gets 16 whole images ->
  // adjacent bands share halo rows in that XCD's L2.
  const int bid = blockIdx.x;
  const int logical = (bid & 7) * 112 + (bid >> 3);
  const int n = logical / 7;
  const int band = logical - n * 7;
  const int h0 = band * TILE_H;

  // staging source pointers: 10 slots/thread; slot s = it*256 + tid holds
  // granule g = (s&7) ^ ((c+4r)&7) of halo cell (r,c). OOB -> zeropage.
  const char* srcp[10];
#pragma unroll
  for (int it = 0; it < 10; ++it) {
    const int s = it * 256 + tid;
    const int rc = s >> 3;
    const int r = rc / HALO_W;
    const int c = rc - r * HALO_W;
    const int g = (s & 7) ^ ((c + 4 * r) & 7);
    const int ih = h0 - 2 + r;
    const int ic = c - 3;
    const bool valid = (rc < RC_SLOTS) & (ih >= 0) & (ih < RR) & (ic >= 0) & (ic < RR);
    srcp[it] = valid
        ? (const char*)(Xin + ((size_t)(n * PLANE + ih * RR + ic)) * CPAD + g * 8)
        : (const char*)g_zeropage;
  }

  // per-M-fragment LDS read bases (7 fragments of 16 positions)
  int baseoff[7], key0[7];
#pragma unroll
  for (int m = 0; m < 7; ++m) {
    const int pos = m * 16 + l15;
    const int hr = pos / RR;
    const int wc = pos - hr * RR;
    baseoff[m] = ((hr + 2) * HALO_W + (wc + 3)) * 128;
    key0[m] = ((wc + 3) + 4 * (hr + 2)) & 7;
  }

  // fragment-ordered weight base for this wave
  const bf16x8* __restrict__ Wf = (const bf16x8*)Wt;
  const int wfbase = wv * 512 + lane;

  f32x4 acc[7][4];
#pragma unroll
  for (int m = 0; m < 7; ++m)
#pragma unroll
    for (int j = 0; j < 4; ++j) acc[m][j] = (f32x4){0.f, 0.f, 0.f, 0.f};

  // prologue: stage chunk 0 into buf0
#pragma unroll
  for (int it = 0; it < 10; ++it)
    load16((char*)Abuf[0] + it * 4096 + wv * 1024, srcp[it]);

#pragma unroll 1
  for (int kc = 0; kc < NK; ++kc) {
    const uint16_t* curbuf = Abuf[kc & 1];
    if (kc + 1 < NK) {
      char* nb = (char*)Abuf[(kc + 1) & 1];
      const int off = (kc + 1) * 128;
#pragma unroll
      for (int it = 0; it < 10; ++it)
        load16(nb + it * 4096 + wv * 1024, srcp[it] + off);
      // keep the 10 just-issued next-chunk loads in flight; drain older ones
      asm volatile("s_waitcnt vmcnt(10)" ::: "memory");
    } else {
      asm volatile("s_waitcnt vmcnt(0)" ::: "memory");
    }
    __builtin_amdgcn_s_barrier();
    asm volatile("" ::: "memory");

    const bf16x8* __restrict__ Wkc = Wf + (size_t)kc * 2048 + wfbase;
#pragma unroll
    for (int t = 0; t < 9; ++t) {
      const int dh = TDH[t], dw = TDW[t];
      bf16x8 bfrag[2][4];
#pragma unroll
      for (int kh = 0; kh < 2; ++kh)
#pragma unroll
        for (int j = 0; j < 4; ++j)
          bfrag[kh][j] = Wkc[(size_t)t * (NK * 2048) + kh * 256 + j * 64];
      const int toff = (dh * HALO_W + dw) * 128;
#pragma unroll
      for (int kh = 0; kh < 2; ++kh) {
        const int kq = kh * 4 + q;
        bf16x8 af[7];
#pragma unroll
        for (int m = 0; m < 7; ++m) {
          const int keyt = (key0[m] + dw + 4 * dh) & 7;
          const int boff = baseoff[m] + toff + ((kq ^ keyt) << 4);
          af[m] = *(const bf16x8*)((const char*)curbuf + boff);
        }
        __builtin_amdgcn_s_setprio(1);
#pragma unroll
        for (int m = 0; m < 7; ++m)
#pragma unroll
          for (int j = 0; j < 4; ++j)
            acc[m][j] = __builtin_amdgcn_mfma_f32_16x16x32_bf16(af[m], bfrag[kh][j],
                                                                acc[m][j], 0, 0, 0);
        __builtin_amdgcn_s_setprio(0);
      }
    }
    asm volatile("" ::: "memory");
    __builtin_amdgcn_s_barrier();
  }

  // epilogue: C/D mapping col=lane&15 (oc), row=(lane>>4)*4+reg (position)
  const int pbase = n * PLANE + h0 * RR;
  if (!FINAL) {
#pragma unroll
    for (int m = 0; m < 7; ++m) {
#pragma unroll
      for (int r = 0; r < 4; ++r) {
        const int gpos = pbase + m * 16 + q * 4 + r;
        uint16_t* row = Yout + (size_t)gpos * HID + ocw + l15;
#pragma unroll
        for (int j = 0; j < 4; ++j) row[j * 16] = f2bf(fmaxf(acc[m][j][r], 0.f));
      }
    }
  } else {
#pragma unroll
    for (int m = 0; m < 7; ++m) {
      const int p4 = m * 16 + q * 4;      // tile-local, multiple of 4, no row-cross
      const int hh = p4 / RR;
      const int ww = p4 - hh * RR;
#pragma unroll
      for (int j = 0; j < 4; ++j) {
        const int o = ocw + j * 16 + l15;
        f32x4 v = acc[m][j];
        v[0] = fmaxf(v[0], 0.f);
        v[1] = fmaxf(v[1], 0.f);
        v[2] = fmaxf(v[2], 0.f);
        v[3] = fmaxf(v[3], 0.f);
        *(f32x4*)(Fout + ((size_t)(n * HID + o)) * PLANE + (h0 + hh) * RR + ww) = v;
      }
    }
  }
}

extern "C" void kernel_launch(void* const* d_in, const int* in_sizes, int n_in,
                              void* d_out, int out_size, void* d_ws, size_t ws_size,
                              hipStream_t stream) {
  const float* feat = (const float*)d_in[0];
  const float* fseg = (const float*)d_in[1];
  const float* w1 = (const float*)d_in[2];
  const float* w2 = (const float*)d_in[3];
  const float* w3 = (const float*)d_in[4];
  const float* w4 = (const float*)d_in[5];
  float* out = (float*)d_out;

  uint8_t* p = (uint8_t*)d_ws;
  uint16_t* X0 = (uint16_t*)p; p += (size_t)P_TOTAL * C1P * 2;   // 115.6 MB
  uint16_t* XA = (uint16_t*)p; p += (size_t)P_TOTAL * HID * 2;   // 51.4 MB
  uint16_t* XB = (uint16_t*)p; p += (size_t)P_TOTAL * HID * 2;   // 51.4 MB
  float* pooled = (float*)p;   p += (size_t)N_IMG * NP1 * PLANE * 4; // 10.0 MB
  uint16_t* W1b = (uint16_t*)p; p += (size_t)9 * HID * C1P * 2;  // 2.65 MB
  uint16_t* W2b = (uint16_t*)p; p += (size_t)9 * HID * HID * 2;  // 1.18 MB
  uint16_t* W3b = (uint16_t*)p; p += (size_t)9 * HID * HID * 2;
  uint16_t* W4b = (uint16_t*)p; p += (size_t)9 * HID * HID * 2;

  // front-end
  pool_kernel<<<(N_IMG * NP1 * PLANE + 255) / 256, 256, 0, stream>>>(fseg, pooled);
  wconv_kernel<<<(9 * HID * C1P + 255) / 256, 256, 0, stream>>>(w1, W1b, C1, C1P);
  wconv_kernel<<<(9 * HID * HID + 255) / 256, 256, 0, stream>>>(w2, W2b, HID, HID);
  wconv_kernel<<<(9 * HID * HID + 255) / 256, 256, 0, stream>>>(w3, W3b, HID, HID);
  wconv_kernel<<<(9 * HID * HID + 255) / 256, 256, 0, stream>>>(w4, W4b, HID, HID);
  build_x0<<<dim3(13, 9, N_IMG), 256, 0, stream>>>(feat, pooled, X0);

  // 4 deform-conv layers: 896 blocks = 128 images x 7 bands
  const int cgrid = P_TOTAL / (TILE_H * RR);
  conv_halo<C1P, false><<<cgrid, 256, 0, stream>>>(X0, W1b, XA, nullptr);
  conv_halo<HID, false><<<cgrid, 256, 0, stream>>>(XA, W2b, XB, nullptr);
  conv_halo<HID, false><<<cgrid, 256, 0, stream>>>(XB, W3b, XA, nullptr);
  conv_halo<HID, true><<<cgrid, 256, 0, stream>>>(XA, W4b, nullptr, out);
}